// Round 10
// baseline (442.003 us; speedup 1.0000x reference)
//
#include <hip/hip_runtime.h>
#include <hip/hip_bf16.h>

// EdgeBlock fused MLP:
//   out = relu(concat(edge, node[recv], node[send], g) @ W1 + b1) @ W2 + b2
// E=640000, N=10000, D=128, H=256, O=128.
//
// R10 = hybrid of R9's ownership structure and R5's proven handoff:
//  - R5 algebra: h = relu(edge @ W1[0:128] + Pr[recv] + Ps[send]);
//    Pr/Ps per-node projections (prep kernels unchanged).
//  - Each wave owns 16 edges end-to-end (4 waves x 16 = 64 edges/block):
//    GEMM1 computes all 256 hidden feats per wave -> NO cross-wave X
//    duplication; X B-fragments read directly from global (each lane
//    loads exactly its own fragment; edge row read once per wave).
//  - h handoff through shared Hs[64][256] using R5's EXACT element-XOR
//    formulas and a plain __syncthreads() (known-good). One barrier.
//  - GEMM2: wave reads only its own 16 Hs rows; W2 frags from L2.
// LDS 32 KiB; launch_bounds(256,3) -> no 128-VGPR clamp (R6/R8 spill trap).

typedef __attribute__((ext_vector_type(8))) short bf16x8;
typedef __attribute__((ext_vector_type(4))) float f32x4;
typedef __attribute__((ext_vector_type(2))) unsigned int u32x2;

#define NTILE 10000

static __device__ __forceinline__ unsigned short f2bf(float f) {
    unsigned u = __builtin_bit_cast(unsigned, f);
    u += 0x7FFFu + ((u >> 16) & 1u);
    return (unsigned short)(u >> 16);
}

static __device__ __forceinline__ unsigned cvt_pk_bf16(float lo, float hi) {
    unsigned r;
    asm("v_cvt_pk_bf16_f32 %0, %1, %2" : "=v"(r) : "v"(lo), "v"(hi));
    return r;
}

static __device__ __forceinline__ float bflo(unsigned u) {
    return __builtin_bit_cast(float, u << 16);
}
static __device__ __forceinline__ float bfhi(unsigned u) {
    return __builtin_bit_cast(float, u & 0xFFFF0000u);
}

// ---------------- prep kernels (unchanged from R5) ----------------

__global__ void prep_w1_kernel(const float* __restrict__ W1,
                               ushort* __restrict__ w1f) {
    int id = blockIdx.x * 256 + threadIdx.x;
    if (id >= 16 * 12 * 64) return;
    int l = id & 63, blk = id >> 6;
    int ks = blk % 12, gnt = blk / 12;
    int n  = gnt * 16 + (l & 15);
    int k0 = ks * 32 + (l >> 4) * 8;
    ushort tmp[8];
    #pragma unroll
    for (int j = 0; j < 8; ++j) tmp[j] = f2bf(W1[(k0 + j) * 256 + n]);
    *(bf16x8*)&w1f[(size_t)id * 8] = *(bf16x8*)tmp;
}

__global__ void prep_w2_kernel(const float* __restrict__ W2,
                               ushort* __restrict__ w2f) {
    int id = blockIdx.x * 256 + threadIdx.x;
    if (id >= 8 * 8 * 64) return;
    int l = id & 63, blk = id >> 6;
    int ks = blk % 8, gnt = blk / 8;
    int n  = gnt * 16 + (l & 15);
    int k0 = ks * 32 + (l >> 4) * 8;
    ushort tmp[8];
    #pragma unroll
    for (int j = 0; j < 8; ++j) tmp[j] = f2bf(W2[(k0 + j) * 128 + n]);
    *(bf16x8*)&w2f[(size_t)id * 8] = *(bf16x8*)tmp;
}

__global__ void prep_hbias_kernel(const float* __restrict__ W1,
                                  const float* __restrict__ b1,
                                  const float* __restrict__ g,
                                  float* __restrict__ hbias) {
    int n = threadIdx.x;
    float acc = b1[n];
    for (int k = 0; k < 128; ++k) acc += g[k] * W1[(384 + k) * 256 + n];
    hbias[n] = acc;
}

__global__ __launch_bounds__(256) void prep_proj_kernel(
    const float* __restrict__ node_attr,
    const ushort* __restrict__ w1f,
    const float* __restrict__ hbias,
    ushort* __restrict__ Pr,
    ushort* __restrict__ Ps)
{
    __shared__ ushort Xn[64 * 128];

    const int t = threadIdx.x, l = t & 63, wn = t >> 6;
    const int base = blockIdx.x * 64;
    const int lr = l & 15, q = l >> 4, lk = q * 8;

    #pragma unroll
    for (int p = 0; p < 4; ++p) {
        int chunk = p * 256 + t;
        int r  = chunk >> 4;
        int c0 = (chunk & 15) * 8;
        int node = base + r; if (node >= NTILE) node = NTILE - 1;
        const float4* src = (const float4*)(node_attr + (size_t)node * 128 + c0);
        float4 a = src[0];
        float4 b = src[1];
        uint4 uu = { cvt_pk_bf16(a.x, a.y), cvt_pk_bf16(a.z, a.w),
                     cvt_pk_bf16(b.x, b.y), cvt_pk_bf16(b.z, b.w) };
        *(bf16x8*)&Xn[r * 128 + (c0 ^ ((r & 7) << 3))] = __builtin_bit_cast(bf16x8, uu);
    }
    __syncthreads();

    #pragma unroll
    for (int s = 0; s < 2; ++s) {
        f32x4 acc[4][4];
        #pragma unroll
        for (int mt = 0; mt < 4; ++mt)
            #pragma unroll
            for (int nt = 0; nt < 4; ++nt)
                acc[mt][nt] = (f32x4){0.f, 0.f, 0.f, 0.f};

        #pragma unroll
        for (int ks = 0; ks < 4; ++ks) {
            bf16x8 B[4];
            #pragma unroll
            for (int nt = 0; nt < 4; ++nt)
                B[nt] = *(const bf16x8*)&w1f[
                    (size_t)(((wn * 4 + nt) * 12 + 4 + s * 4 + ks) * 64 + l) * 8];
            bf16x8 X[4];
            const int kk = ks * 32 + lk;
            #pragma unroll
            for (int mt = 0; mt < 4; ++mt) {
                const int row = mt * 16 + lr;
                X[mt] = *(const bf16x8*)&Xn[row * 128 + (kk ^ ((row & 7) << 3))];
            }
            #pragma unroll
            for (int mt = 0; mt < 4; ++mt)
                #pragma unroll
                for (int nt = 0; nt < 4; ++nt)
                    acc[mt][nt] = __builtin_amdgcn_mfma_f32_16x16x32_bf16(
                        B[nt], X[mt], acc[mt][nt], 0, 0, 0);
        }

        ushort* P = s ? Ps : Pr;
        #pragma unroll
        for (int nt = 0; nt < 4; ++nt) {
            const int F = wn * 64 + nt * 16 + q * 4;
            float4 hb4 = {0.f, 0.f, 0.f, 0.f};
            if (s == 0) hb4 = *(const float4*)&hbias[F];
            #pragma unroll
            for (int mt = 0; mt < 4; ++mt) {
                const int node = base + mt * 16 + lr;
                if (node < NTILE) {
                    u32x2 w = { cvt_pk_bf16(acc[mt][nt][0] + hb4.x,
                                            acc[mt][nt][1] + hb4.y),
                                cvt_pk_bf16(acc[mt][nt][2] + hb4.z,
                                            acc[mt][nt][3] + hb4.w) };
                    *(u32x2*)&P[(size_t)node * 256 + F] = w;
                }
            }
        }
    }
}

// ---------------- main kernel: wave-owned edges, R5 handoff ----------------

__global__ __launch_bounds__(256, 3) void edge_mlp_kernel(
    const float* __restrict__ edge_attr,   // [E][128] f32
    const int* __restrict__ senders,
    const int* __restrict__ receivers,
    const ushort* __restrict__ w1f,        // frag-packed (ks 0..3 used)
    const ushort* __restrict__ w2f,        // frag-packed
    const ushort* __restrict__ Pr,         // [10000][256] bf16 (has hbias)
    const ushort* __restrict__ Ps,         // [10000][256] bf16
    const float* __restrict__ b2,          // [128]
    float* __restrict__ out)               // [E][128] f32
{
    __shared__ ushort Hs[64 * 256];   // 32 KiB, R5's exact swizzled layout

    const int t  = threadIdx.x;
    const int l  = t & 63;
    const int w  = t >> 6;        // wave 0..3
    const int lr = l & 15;        // edge within the wave's 16 (MFMA col)
    const int q  = l >> 4;        // lane quarter
    const int row  = w * 16 + lr;               // Hs row (block-local edge)
    const size_t ebase = (size_t)blockIdx.x * 64 + w * 16;  // wave's edges

    // ---- per-lane indices ----
    const int rc = receivers[ebase + lr];
    const int sc = senders[ebase + lr];

    // ---- X fragments: direct global reads (lane reads its own B-frag) ----
    const float* erow = edge_attr + (ebase + lr) * 128;
    bf16x8 X[4];
    #pragma unroll
    for (int ks = 0; ks < 4; ++ks) {
        float4 xa = *(const float4*)(erow + ks * 32 + q * 8);
        float4 xb = *(const float4*)(erow + ks * 32 + q * 8 + 4);
        uint4 uu = { cvt_pk_bf16(xa.x, xa.y), cvt_pk_bf16(xa.z, xa.w),
                     cvt_pk_bf16(xb.x, xb.y), cvt_pk_bf16(xb.z, xb.w) };
        X[ks] = __builtin_bit_cast(bf16x8, uu);
    }

    // ---- P gathers: 32 x 8B (issued early, resolve under GEMM1) ----
    u32x2 pg[16], sg[16];
    #pragma unroll
    for (int nt = 0; nt < 16; ++nt) {
        const int F = nt * 16 + q * 4;
        pg[nt] = *(const u32x2*)&Pr[(size_t)rc * 256 + F];
        sg[nt] = *(const u32x2*)&Ps[(size_t)sc * 256 + F];
    }

    // ---- GEMM1: all 256 hidden feats for the wave's 16 edges ----
    f32x4 acc[16];
    #pragma unroll
    for (int nt = 0; nt < 16; ++nt)
        acc[nt] = (f32x4){0.f, 0.f, 0.f, 0.f};

    #pragma unroll
    for (int ks = 0; ks < 4; ++ks)
        #pragma unroll
        for (int nt = 0; nt < 16; ++nt) {
            bf16x8 Wf = *(const bf16x8*)&w1f[(size_t)((nt * 12 + ks) * 64 + l) * 8];
            acc[nt] = __builtin_amdgcn_mfma_f32_16x16x32_bf16(Wf, X[ks], acc[nt], 0, 0, 0);
        }

    // ---- epilogue 1: +Pr +Ps, relu, cvt_pk -> Hs (R5's exact formulas) ----
    #pragma unroll
    for (int nt = 0; nt < 16; ++nt) {
        u32x2 p = pg[nt], s = sg[nt];
        float v0 = fmaxf(acc[nt][0] + bflo(p.x) + bflo(s.x), 0.f);
        float v1 = fmaxf(acc[nt][1] + bfhi(p.x) + bfhi(s.x), 0.f);
        float v2 = fmaxf(acc[nt][2] + bflo(p.y) + bflo(s.y), 0.f);
        float v3 = fmaxf(acc[nt][3] + bfhi(p.y) + bfhi(s.y), 0.f);
        u32x2 wv = { cvt_pk_bf16(v0, v1), cvt_pk_bf16(v2, v3) };
        const int F = nt * 16 + q * 4;
        *(u32x2*)&Hs[row * 256 + (F ^ ((row & 7) << 3))] = wv;
    }

    __syncthreads();   // known-good handoff sync (R5 pattern)

    // ---- GEMM2: wave's 16 edges x all 128 out feats ----
    f32x4 acc2[8];
    #pragma unroll
    for (int nt = 0; nt < 8; ++nt)
        acc2[nt] = (f32x4){0.f, 0.f, 0.f, 0.f};

    #pragma unroll
    for (int ks = 0; ks < 8; ++ks) {
        const int F0 = ks * 32 + q * 8;
        bf16x8 Hf = *(const bf16x8*)&Hs[row * 256 + (F0 ^ ((row & 7) << 3))];
        #pragma unroll
        for (int nt = 0; nt < 8; ++nt) {
            bf16x8 Wf = *(const bf16x8*)&w2f[(size_t)((nt * 8 + ks) * 64 + l) * 8];
            acc2[nt] = __builtin_amdgcn_mfma_f32_16x16x32_bf16(Wf, Hf, acc2[nt], 0, 0, 0);
        }
    }

    // ---- epilogue 2: +b2, 16B stores ----
    float* orow = out + (ebase + lr) * 128;
    #pragma unroll
    for (int nt = 0; nt < 8; ++nt) {
        const int F = nt * 16 + q * 4;
        float4 b24 = *(const float4*)&b2[F];
        float4 o = { acc2[nt][0] + b24.x, acc2[nt][1] + b24.y,
                     acc2[nt][2] + b24.z, acc2[nt][3] + b24.w };
        *(float4*)(orow + F) = o;
    }
}

// ---------------- launcher ----------------

extern "C" void kernel_launch(void* const* d_in, const int* in_sizes, int n_in,
                              void* d_out, int out_size, void* d_ws, size_t ws_size,
                              hipStream_t stream) {
    (void)in_sizes; (void)n_in; (void)out_size; (void)ws_size;

    const float* edge_attr   = (const float*)d_in[0];
    const float* node_attr   = (const float*)d_in[1];
    const float* global_attr = (const float*)d_in[2];
    const int*   senders     = (const int*)d_in[3];
    const int*   receivers   = (const int*)d_in[4];
    const float* W1          = (const float*)d_in[5];
    const float* b1          = (const float*)d_in[6];
    const float* W2          = (const float*)d_in[7];
    const float* b2          = (const float*)d_in[8];
    float* out = (float*)d_out;

    ushort* w1f   = (ushort*)d_ws;                          //   196,608 B
    ushort* w2f   = (ushort*)((char*)d_ws + 196608);        //    65,536 B
    float*  hbias = (float*)((char*)d_ws + 262144);         //     1,024 B
    ushort* Pr    = (ushort*)((char*)d_ws + 263168);        // 5,120,000 B
    ushort* Ps    = (ushort*)((char*)d_ws + 5383168);       // 5,120,000 B

    hipLaunchKernelGGL(prep_w1_kernel,    dim3(48),  dim3(256), 0, stream, W1, w1f);
    hipLaunchKernelGGL(prep_w2_kernel,    dim3(16),  dim3(256), 0, stream, W2, w2f);
    hipLaunchKernelGGL(prep_hbias_kernel, dim3(1),   dim3(256), 0, stream, W1, b1, global_attr, hbias);
    hipLaunchKernelGGL(prep_proj_kernel,  dim3(157), dim3(256), 0, stream,
                       node_attr, w1f, hbias, Pr, Ps);

    hipLaunchKernelGGL(edge_mlp_kernel, dim3(10000), dim3(256), 0, stream,
                       edge_attr, senders, receivers, w1f, w2f, Pr, Ps, b2, out);
}

// Round 11
// 326.086 us; speedup vs baseline: 1.3555x; 1.3555x over previous
//
#include <hip/hip_runtime.h>
#include <hip/hip_bf16.h>

// EdgeBlock fused MLP:
//   out = relu(concat(edge, node[recv], node[send], g) @ W1 + b1) @ W2 + b2
// E=640000, N=10000, D=128, H=256, O=128.
//
// R11: request-rate attack. Cross-round counter analysis shows all designs
// plateau at ~85-90G L2 line-requests/s with every pipe idle -> treat
// vector-memory REQUEST COUNT as the resource. Dominant reducible term:
// weight-fragment re-reads (128KB per block). Fix: BM=128 edges, 8 waves,
// STRICT nt-split (GEMM1 2 nt/wave, GEMM2 1 nt/wave, all 8 m-tiles each)
// -> weight requests per edge HALVED vs R5. Everything else is R5 verbatim:
//   - algebra: h = relu(edge @ W1[0:128] + Pr[recv] + Ps[send])
//   - Xe staged once (swizzled bf16), Hs handoff formulas, plain barriers.
//   - Xe aliased under Hs (64KB LDS -> 2 blocks/CU); barrier #2 protects
//     the alias (all Xe reads precede all Hs writes).

typedef __attribute__((ext_vector_type(8))) short bf16x8;
typedef __attribute__((ext_vector_type(4))) float f32x4;
typedef __attribute__((ext_vector_type(2))) unsigned int u32x2;

#define NTILE 10000

static __device__ __forceinline__ unsigned short f2bf(float f) {
    unsigned u = __builtin_bit_cast(unsigned, f);
    u += 0x7FFFu + ((u >> 16) & 1u);
    return (unsigned short)(u >> 16);
}

static __device__ __forceinline__ unsigned cvt_pk_bf16(float lo, float hi) {
    unsigned r;
    asm("v_cvt_pk_bf16_f32 %0, %1, %2" : "=v"(r) : "v"(lo), "v"(hi));
    return r;
}

static __device__ __forceinline__ float bflo(unsigned u) {
    return __builtin_bit_cast(float, u << 16);
}
static __device__ __forceinline__ float bfhi(unsigned u) {
    return __builtin_bit_cast(float, u & 0xFFFF0000u);
}

// ---------------- prep kernels (unchanged from R5) ----------------

__global__ void prep_w1_kernel(const float* __restrict__ W1,
                               ushort* __restrict__ w1f) {
    int id = blockIdx.x * 256 + threadIdx.x;
    if (id >= 16 * 12 * 64) return;
    int l = id & 63, blk = id >> 6;
    int ks = blk % 12, gnt = blk / 12;
    int n  = gnt * 16 + (l & 15);
    int k0 = ks * 32 + (l >> 4) * 8;
    ushort tmp[8];
    #pragma unroll
    for (int j = 0; j < 8; ++j) tmp[j] = f2bf(W1[(k0 + j) * 256 + n]);
    *(bf16x8*)&w1f[(size_t)id * 8] = *(bf16x8*)tmp;
}

__global__ void prep_w2_kernel(const float* __restrict__ W2,
                               ushort* __restrict__ w2f) {
    int id = blockIdx.x * 256 + threadIdx.x;
    if (id >= 8 * 8 * 64) return;
    int l = id & 63, blk = id >> 6;
    int ks = blk % 8, gnt = blk / 8;
    int n  = gnt * 16 + (l & 15);
    int k0 = ks * 32 + (l >> 4) * 8;
    ushort tmp[8];
    #pragma unroll
    for (int j = 0; j < 8; ++j) tmp[j] = f2bf(W2[(k0 + j) * 128 + n]);
    *(bf16x8*)&w2f[(size_t)id * 8] = *(bf16x8*)tmp;
}

__global__ void prep_hbias_kernel(const float* __restrict__ W1,
                                  const float* __restrict__ b1,
                                  const float* __restrict__ g,
                                  float* __restrict__ hbias) {
    int n = threadIdx.x;
    float acc = b1[n];
    for (int k = 0; k < 128; ++k) acc += g[k] * W1[(384 + k) * 256 + n];
    hbias[n] = acc;
}

__global__ __launch_bounds__(256) void prep_proj_kernel(
    const float* __restrict__ node_attr,
    const ushort* __restrict__ w1f,
    const float* __restrict__ hbias,
    ushort* __restrict__ Pr,
    ushort* __restrict__ Ps)
{
    __shared__ ushort Xn[64 * 128];

    const int t = threadIdx.x, l = t & 63, wn = t >> 6;
    const int base = blockIdx.x * 64;
    const int lr = l & 15, q = l >> 4, lk = q * 8;

    #pragma unroll
    for (int p = 0; p < 4; ++p) {
        int chunk = p * 256 + t;
        int r  = chunk >> 4;
        int c0 = (chunk & 15) * 8;
        int node = base + r; if (node >= NTILE) node = NTILE - 1;
        const float4* src = (const float4*)(node_attr + (size_t)node * 128 + c0);
        float4 a = src[0];
        float4 b = src[1];
        uint4 uu = { cvt_pk_bf16(a.x, a.y), cvt_pk_bf16(a.z, a.w),
                     cvt_pk_bf16(b.x, b.y), cvt_pk_bf16(b.z, b.w) };
        *(bf16x8*)&Xn[r * 128 + (c0 ^ ((r & 7) << 3))] = __builtin_bit_cast(bf16x8, uu);
    }
    __syncthreads();

    #pragma unroll
    for (int s = 0; s < 2; ++s) {
        f32x4 acc[4][4];
        #pragma unroll
        for (int mt = 0; mt < 4; ++mt)
            #pragma unroll
            for (int nt = 0; nt < 4; ++nt)
                acc[mt][nt] = (f32x4){0.f, 0.f, 0.f, 0.f};

        #pragma unroll
        for (int ks = 0; ks < 4; ++ks) {
            bf16x8 B[4];
            #pragma unroll
            for (int nt = 0; nt < 4; ++nt)
                B[nt] = *(const bf16x8*)&w1f[
                    (size_t)(((wn * 4 + nt) * 12 + 4 + s * 4 + ks) * 64 + l) * 8];
            bf16x8 X[4];
            const int kk = ks * 32 + lk;
            #pragma unroll
            for (int mt = 0; mt < 4; ++mt) {
                const int row = mt * 16 + lr;
                X[mt] = *(const bf16x8*)&Xn[row * 128 + (kk ^ ((row & 7) << 3))];
            }
            #pragma unroll
            for (int mt = 0; mt < 4; ++mt)
                #pragma unroll
                for (int nt = 0; nt < 4; ++nt)
                    acc[mt][nt] = __builtin_amdgcn_mfma_f32_16x16x32_bf16(
                        B[nt], X[mt], acc[mt][nt], 0, 0, 0);
        }

        ushort* P = s ? Ps : Pr;
        #pragma unroll
        for (int nt = 0; nt < 4; ++nt) {
            const int F = wn * 64 + nt * 16 + q * 4;
            float4 hb4 = {0.f, 0.f, 0.f, 0.f};
            if (s == 0) hb4 = *(const float4*)&hbias[F];
            #pragma unroll
            for (int mt = 0; mt < 4; ++mt) {
                const int node = base + mt * 16 + lr;
                if (node < NTILE) {
                    u32x2 w = { cvt_pk_bf16(acc[mt][nt][0] + hb4.x,
                                            acc[mt][nt][1] + hb4.y),
                                cvt_pk_bf16(acc[mt][nt][2] + hb4.z,
                                            acc[mt][nt][3] + hb4.w) };
                    *(u32x2*)&P[(size_t)node * 256 + F] = w;
                }
            }
        }
    }
}

// ---------------- main kernel: BM=128, 8 waves, strict nt-split ----------------

__global__ __launch_bounds__(512) void edge_mlp_kernel(
    const float* __restrict__ edge_attr,   // [E][128] f32
    const int* __restrict__ senders,
    const int* __restrict__ receivers,
    const ushort* __restrict__ w1f,        // frag-packed (ks 0..3 used)
    const ushort* __restrict__ w2f,        // frag-packed
    const ushort* __restrict__ Pr,         // [10000][256] bf16 (has hbias)
    const ushort* __restrict__ Ps,         // [10000][256] bf16
    const float* __restrict__ b2,          // [128]
    float* __restrict__ out)               // [E][128] f32
{
    // 64 KiB shared, aliased: Xe = first 32 KiB ([128 edges][128 feats]),
    // Hs = full 64 KiB ([128 edges][256 feats]); both XOR-swizzled.
    // Barrier #2 (post-GEMM1) guarantees all Xe reads precede Hs writes.
    __shared__ ushort Lds[128 * 256];
    ushort* Xe = Lds;
    ushort* Hs = Lds;

    const int t  = threadIdx.x;
    const int l  = t & 63;
    const int w  = t >> 6;        // wave 0..7
    const int lr = l & 15;
    const int q  = l >> 4;
    const int base = blockIdx.x * 128;

    // ---- stage edge segment: 128 rows f32 -> bf16 swizzled Xe ----
    #pragma unroll
    for (int p = 0; p < 4; ++p) {
        int chunk = p * 512 + t;           // 0..2047: 128 rows x 16 chunks
        int r  = chunk >> 4;
        int c0 = (chunk & 15) * 8;
        const float4* src = (const float4*)(edge_attr + (size_t)(base + r) * 128 + c0);
        float4 a = src[0];
        float4 b = src[1];
        uint4 uu = { cvt_pk_bf16(a.x, a.y), cvt_pk_bf16(a.z, a.w),
                     cvt_pk_bf16(b.x, b.y), cvt_pk_bf16(b.z, b.w) };
        *(bf16x8*)&Xe[r * 128 + (c0 ^ ((r & 7) << 3))] = __builtin_bit_cast(bf16x8, uu);
    }

    __syncthreads();   // #1: Xe ready

    // ---- GEMM1: wave w owns hidden nt {2w, 2w+1}, all 8 m-tiles ----
    f32x4 acc[8][2];   // [mt][ntl]
    #pragma unroll
    for (int mt = 0; mt < 8; ++mt)
        #pragma unroll
        for (int ntl = 0; ntl < 2; ++ntl)
            acc[mt][ntl] = (f32x4){0.f, 0.f, 0.f, 0.f};

    #pragma unroll
    for (int ks = 0; ks < 4; ++ks) {
        bf16x8 B[2];
        #pragma unroll
        for (int ntl = 0; ntl < 2; ++ntl)
            B[ntl] = *(const bf16x8*)&w1f[
                (size_t)(((w * 2 + ntl) * 12 + ks) * 64 + l) * 8];
        const int kk = ks * 32 + q * 8;
        #pragma unroll
        for (int mt = 0; mt < 8; ++mt) {
            const int row = mt * 16 + lr;
            bf16x8 X = *(const bf16x8*)&Xe[row * 128 + (kk ^ ((row & 7) << 3))];
            #pragma unroll
            for (int ntl = 0; ntl < 2; ++ntl)
                acc[mt][ntl] = __builtin_amdgcn_mfma_f32_16x16x32_bf16(
                    B[ntl], X, acc[mt][ntl], 0, 0, 0);
        }
    }

    __syncthreads();   // #2: all Xe reads done -> Hs may overwrite alias

    // ---- P gathers + epilogue 1 -> swizzled Hs (R5's exact formulas) ----
    #pragma unroll
    for (int mt = 0; mt < 8; ++mt) {
        const int e  = base + mt * 16 + lr;
        const int rc = receivers[e];
        const int sc = senders[e];
        #pragma unroll
        for (int ntl = 0; ntl < 2; ++ntl) {
            const int F = w * 32 + ntl * 16 + q * 4;
            u32x2 p = *(const u32x2*)&Pr[(size_t)rc * 256 + F];
            u32x2 s = *(const u32x2*)&Ps[(size_t)sc * 256 + F];
            float v0 = fmaxf(acc[mt][ntl][0] + bflo(p.x) + bflo(s.x), 0.f);
            float v1 = fmaxf(acc[mt][ntl][1] + bfhi(p.x) + bfhi(s.x), 0.f);
            float v2 = fmaxf(acc[mt][ntl][2] + bflo(p.y) + bflo(s.y), 0.f);
            float v3 = fmaxf(acc[mt][ntl][3] + bfhi(p.y) + bfhi(s.y), 0.f);
            u32x2 wv = { cvt_pk_bf16(v0, v1), cvt_pk_bf16(v2, v3) };
            const int row = mt * 16 + lr;
            *(u32x2*)&Hs[row * 256 + (F ^ ((row & 7) << 3))] = wv;
        }
    }

    __syncthreads();   // #3: Hs ready

    // ---- GEMM2: wave w owns out-nt = w (16 feats), all 8 m-tiles ----
    f32x4 acc2[8];
    #pragma unroll
    for (int mt = 0; mt < 8; ++mt)
        acc2[mt] = (f32x4){0.f, 0.f, 0.f, 0.f};

    #pragma unroll
    for (int ks = 0; ks < 8; ++ks) {
        bf16x8 Wf = *(const bf16x8*)&w2f[(size_t)((w * 8 + ks) * 64 + l) * 8];
        const int F0 = ks * 32 + q * 8;
        #pragma unroll
        for (int mt = 0; mt < 8; ++mt) {
            const int row = mt * 16 + lr;
            bf16x8 Hf = *(const bf16x8*)&Hs[row * 256 + (F0 ^ ((row & 7) << 3))];
            acc2[mt] = __builtin_amdgcn_mfma_f32_16x16x32_bf16(Wf, Hf, acc2[mt], 0, 0, 0);
        }
    }

    // ---- epilogue 2: +b2, 16B stores (4 q-lanes -> 64B/row per instr) ----
    const int F2 = w * 16 + q * 4;
    float4 b24 = *(const float4*)&b2[F2];
    #pragma unroll
    for (int mt = 0; mt < 8; ++mt) {
        const int e = base + mt * 16 + lr;
        float4 o = { acc2[mt][0] + b24.x, acc2[mt][1] + b24.y,
                     acc2[mt][2] + b24.z, acc2[mt][3] + b24.w };
        *(float4*)&out[(size_t)e * 128 + F2] = o;
    }
}

// ---------------- launcher ----------------

extern "C" void kernel_launch(void* const* d_in, const int* in_sizes, int n_in,
                              void* d_out, int out_size, void* d_ws, size_t ws_size,
                              hipStream_t stream) {
    (void)in_sizes; (void)n_in; (void)out_size; (void)ws_size;

    const float* edge_attr   = (const float*)d_in[0];
    const float* node_attr   = (const float*)d_in[1];
    const float* global_attr = (const float*)d_in[2];
    const int*   senders     = (const int*)d_in[3];
    const int*   receivers   = (const int*)d_in[4];
    const float* W1          = (const float*)d_in[5];
    const float* b1          = (const float*)d_in[6];
    const float* W2          = (const float*)d_in[7];
    const float* b2          = (const float*)d_in[8];
    float* out = (float*)d_out;

    ushort* w1f   = (ushort*)d_ws;                          //   196,608 B
    ushort* w2f   = (ushort*)((char*)d_ws + 196608);        //    65,536 B
    float*  hbias = (float*)((char*)d_ws + 262144);         //     1,024 B
    ushort* Pr    = (ushort*)((char*)d_ws + 263168);        // 5,120,000 B
    ushort* Ps    = (ushort*)((char*)d_ws + 5383168);       // 5,120,000 B

    hipLaunchKernelGGL(prep_w1_kernel,    dim3(48),  dim3(256), 0, stream, W1, w1f);
    hipLaunchKernelGGL(prep_w2_kernel,    dim3(16),  dim3(256), 0, stream, W2, w2f);
    hipLaunchKernelGGL(prep_hbias_kernel, dim3(1),   dim3(256), 0, stream, W1, b1, global_attr, hbias);
    hipLaunchKernelGGL(prep_proj_kernel,  dim3(157), dim3(256), 0, stream,
                       node_attr, w1f, hbias, Pr, Ps);

    hipLaunchKernelGGL(edge_mlp_kernel, dim3(5000), dim3(512), 0, stream,
                       edge_attr, senders, receivers, w1f, w2f, Pr, Ps, b2, out);
}